// Round 8
// baseline (753.525 us; speedup 1.0000x reference)
//
#include <hip/hip_runtime.h>
#include <cmath>

#define N_NODES 100000
#define N_EDGES 1600000
#define IN_DIM 128
#define HID 96
#define NCLS 16
#define NB_SCAN 391   // ceil(N_NODES/256)
#define NB_GATH 2048  // gather grid (fixed, for stats partials)

// two-level CSR bucketing
#define BSHIFT 7
#define BNODES 128                 // nodes per bucket
#define NBUK 782                   // ceil(N_NODES/128)
#define BCAP 2560                  // max edges per bucket (mean 2046, +11 sigma)

typedef unsigned int uint;
typedef unsigned short ushort;
typedef int iv4 __attribute__((ext_vector_type(4)));

__device__ __forceinline__ int4 ntload4(const int* __restrict__ p) {
    iv4 v = __builtin_nontemporal_load((const iv4*)p);
    return make_int4(v.x, v.y, v.z, v.w);
}

__device__ __forceinline__ ushort f2bf(float x) {  // RNE f32->bf16
    uint b = __float_as_uint(x);
    uint r = (b + 0x7FFFu + ((b >> 16) & 1u)) >> 16;
    return (ushort)r;
}
__device__ __forceinline__ float bf2f(ushort u) {
    return __uint_as_float(((uint)u) << 16);
}
__device__ __forceinline__ float4 bn_relu4(float4 x, float4 sc, float4 sh) {
    float4 r;
    r.x = fmaxf(fmaf(x.x, sc.x, sh.x), 0.f);
    r.y = fmaxf(fmaf(x.y, sc.y, sh.y), 0.f);
    r.z = fmaxf(fmaf(x.z, sc.z, sh.z), 0.f);
    r.w = fmaxf(fmaf(x.w, sc.w, sh.w), 0.f);
    return r;
}
__device__ __forceinline__ void acc4(float4& a, float4 x) {
    a.x += x.x; a.y += x.y; a.z += x.z; a.w += x.w;
}

// ---------------------------------------------------------------------------
// wfuse: Wf[128][96] = W_emb @ W1 ; bf[96] = b_emb @ W1
// ---------------------------------------------------------------------------
__global__ __launch_bounds__(256) void wfuse(const float* __restrict__ W_emb,
                                             const float* __restrict__ W1,
                                             const float* __restrict__ b_emb,
                                             float* __restrict__ Wf,
                                             float* __restrict__ bf) {
    __shared__ float W1s[HID * HID];
    for (int i = threadIdx.x; i < HID * HID / 4; i += 256)
        ((float4*)W1s)[i] = ((const float4*)W1)[i];
    __syncthreads();
    int idx = blockIdx.x * 256 + threadIdx.x;
    if (idx < IN_DIM * HID) {
        int i = idx / HID, j = idx - (idx / HID) * HID;
        float acc = 0.f;
        for (int k = 0; k < HID; ++k)
            acc = fmaf(W_emb[(size_t)i * HID + k], W1s[k * HID + j], acc);
        Wf[idx] = acc;
    }
    if (idx < HID) {
        float acc = 0.f;
        for (int k = 0; k < HID; ++k)
            acc = fmaf(b_emb[k], W1s[k * HID + idx], acc);
        bf[idx] = acc;
    }
}

// ---------------------------------------------------------------------------
// Tiled GEMM -> bf16 table (unchanged from round 6/7).
// ---------------------------------------------------------------------------
template <int K, bool BNIN>
__global__ __launch_bounds__(192) void gemm_bf16(const float* __restrict__ X,
                                                 const float* __restrict__ W,
                                                 const float* __restrict__ bias,
                                                 const float* __restrict__ scale,
                                                 const float* __restrict__ shift,
                                                 ushort* __restrict__ outB) {
    constexpr int GSTRIDE = K * 16 + 4;
    __shared__ float Ws[6 * GSTRIDE];
    __shared__ float bs[HID];
    __shared__ float scs[HID], shs[HID];
    for (int i = threadIdx.x; i < K * HID / 4; i += 192) {
        int flat = i * 4;
        int k = flat / HID, c = flat - k * HID;
        int g = c / 16, j = c - g * 16;
        *(float4*)&Ws[g * GSTRIDE + k * 16 + j] = ((const float4*)W)[i];
    }
    if (threadIdx.x < HID) {
        bs[threadIdx.x] = bias ? bias[threadIdx.x] : 0.f;
        if (BNIN) {
            scs[threadIdx.x] = scale[threadIdx.x];
            shs[threadIdx.x] = shift[threadIdx.x];
        }
    }
    __syncthreads();

    const int g = threadIdx.x % 6;
    const int rc = threadIdx.x / 6;
    const int rbase = blockIdx.x * 128 + rc * 4;
    const int r0 = min(rbase + 0, N_NODES - 1);
    const int r1 = min(rbase + 1, N_NODES - 1);
    const int r2 = min(rbase + 2, N_NODES - 1);
    const int r3 = min(rbase + 3, N_NODES - 1);
    const float* x0 = X + (size_t)r0 * K;
    const float* x1 = X + (size_t)r1 * K;
    const float* x2 = X + (size_t)r2 * K;
    const float* x3 = X + (size_t)r3 * K;
    const float* wg = Ws + g * GSTRIDE;

    float acc[4][16];
#pragma unroll
    for (int j = 0; j < 16; ++j) {
        float bj = bs[g * 16 + j];
        acc[0][j] = bj; acc[1][j] = bj; acc[2][j] = bj; acc[3][j] = bj;
    }

    for (int k = 0; k < K; k += 4) {
        float4 a0 = *(const float4*)(x0 + k);
        float4 a1 = *(const float4*)(x1 + k);
        float4 a2 = *(const float4*)(x2 + k);
        float4 a3 = *(const float4*)(x3 + k);
        if (BNIN) {
            float4 sc4 = *(const float4*)(scs + k);
            float4 sh4 = *(const float4*)(shs + k);
            a0 = bn_relu4(a0, sc4, sh4);
            a1 = bn_relu4(a1, sc4, sh4);
            a2 = bn_relu4(a2, sc4, sh4);
            a3 = bn_relu4(a3, sc4, sh4);
        }
#pragma unroll
        for (int kk = 0; kk < 4; ++kk) {
            const float* wrow = wg + (k + kk) * 16;
            float4 w0 = *(const float4*)(wrow + 0);
            float4 w1 = *(const float4*)(wrow + 4);
            float4 w2 = *(const float4*)(wrow + 8);
            float4 w3 = *(const float4*)(wrow + 12);
            float xs0 = kk == 0 ? a0.x : kk == 1 ? a0.y : kk == 2 ? a0.z : a0.w;
            float xs1 = kk == 0 ? a1.x : kk == 1 ? a1.y : kk == 2 ? a1.z : a1.w;
            float xs2 = kk == 0 ? a2.x : kk == 1 ? a2.y : kk == 2 ? a2.z : a2.w;
            float xs3 = kk == 0 ? a3.x : kk == 1 ? a3.y : kk == 2 ? a3.z : a3.w;
            const float wv[16] = {w0.x, w0.y, w0.z, w0.w, w1.x, w1.y, w1.z, w1.w,
                                  w2.x, w2.y, w2.z, w2.w, w3.x, w3.y, w3.z, w3.w};
#pragma unroll
            for (int j = 0; j < 16; ++j) {
                acc[0][j] = fmaf(xs0, wv[j], acc[0][j]);
                acc[1][j] = fmaf(xs1, wv[j], acc[1][j]);
                acc[2][j] = fmaf(xs2, wv[j], acc[2][j]);
                acc[3][j] = fmaf(xs3, wv[j], acc[3][j]);
            }
        }
    }
    const int rr[4] = {r0, r1, r2, r3};
    union PK { ushort u[8]; uint4 v; };
#pragma unroll
    for (int i = 0; i < 4; ++i) {
        ushort* orow = outB + (size_t)rr[i] * HID + g * 16;
        PK p0, p1;
#pragma unroll
        for (int j = 0; j < 8; ++j) {
            p0.u[j] = f2bf(acc[i][j]);
            p1.u[j] = f2bf(acc[i][j + 8]);
        }
        *(uint4*)(orow + 0) = p0.v;
        *(uint4*)(orow + 8) = p1.v;
    }
}

// ---------------------------------------------------------------------------
// CSR build, two-level bucketing. Bucket writes fill front-to-back in TIME
// order (cursor-ordered), so each 64B line is completed within a short
// window and written back once -- kills the 10x RFO/writeback amplification
// of per-node scatter (rounds 6/7).
// ---------------------------------------------------------------------------
__global__ __launch_bounds__(256) void bucket_scatter(const int* __restrict__ src,
                                                      const int* __restrict__ dst,
                                                      int* __restrict__ bcur,
                                                      int* __restrict__ bsrc,
                                                      int* __restrict__ bdst) {
    int i = blockIdx.x * 256 + threadIdx.x;
    if (i >= N_EDGES / 4) return;
    int4 d = ntload4(dst + i * 4);
    int4 s = ntload4(src + i * 4);
#pragma unroll
    for (int e = 0; e < 4; ++e) {
        int dv = e == 0 ? d.x : e == 1 ? d.y : e == 2 ? d.z : d.w;
        int sv = e == 0 ? s.x : e == 1 ? s.y : e == 2 ? s.z : s.w;
        int b = dv >> BSHIFT;
        int pos = atomicAdd(&bcur[b], 1);
        if (pos < BCAP) {
            bsrc[(size_t)b * BCAP + pos] = sv;
            bdst[(size_t)b * BCAP + pos] = dv;
        }
    }
}

// one block per bucket: LDS histogram of local degrees -> dense deg write
__global__ __launch_bounds__(256) void bucket_hist(const int* __restrict__ bdst,
                                                   const int* __restrict__ bcur,
                                                   int* __restrict__ deg) {
    int b = blockIdx.x;
    int lo = b << BSHIFT;
    __shared__ int cnt[BNODES];
    if (threadIdx.x < BNODES) cnt[threadIdx.x] = 0;
    __syncthreads();
    int n = min(bcur[b], BCAP);
    const int* bd = bdst + (size_t)b * BCAP;
    for (int i = threadIdx.x; i < n; i += 256) atomicAdd(&cnt[bd[i] - lo], 1);
    __syncthreads();
    if (threadIdx.x < BNODES && lo + threadIdx.x < N_NODES)
        deg[lo + threadIdx.x] = cnt[threadIdx.x];
}

// one block per bucket: scatter into cols within the bucket's small window
__global__ __launch_bounds__(256) void bucket_place(const int* __restrict__ bsrc,
                                                    const int* __restrict__ bdst,
                                                    const int* __restrict__ bcur,
                                                    const int* __restrict__ rp,
                                                    int* __restrict__ cols) {
    int b = blockIdx.x;
    int lo = b << BSHIFT;
    __shared__ int cur[BNODES];
    if (threadIdx.x < BNODES && lo + threadIdx.x < N_NODES)
        cur[threadIdx.x] = rp[lo + threadIdx.x];
    __syncthreads();
    int n = min(bcur[b], BCAP);
    const int* bd = bdst + (size_t)b * BCAP;
    const int* bsp = bsrc + (size_t)b * BCAP;
    for (int i = threadIdx.x; i < n; i += 256) {
        int p = atomicAdd(&cur[bd[i] - lo], 1);
        cols[p] = bsp[i];
    }
}

// ---------------------------------------------------------------------------
// Scan (2-level) over deg -> rp
// ---------------------------------------------------------------------------
__global__ void scan_blocksum(const int* __restrict__ deg, int* __restrict__ bsums) {
    __shared__ int sm[256];
    int t = threadIdx.x;
    int i = blockIdx.x * 256 + t;
    sm[t] = (i < N_NODES) ? deg[i] : 0;
    __syncthreads();
    for (int s = 128; s > 0; s >>= 1) {
        if (t < s) sm[t] += sm[t + s];
        __syncthreads();
    }
    if (t == 0) bsums[blockIdx.x] = sm[0];
}

__global__ void scan_offsets(const int* __restrict__ bsums, int* __restrict__ boffs) {
    __shared__ int tmp[512];
    int t = threadIdx.x;
    int v = (t < NB_SCAN) ? bsums[t] : 0;
    tmp[t] = v;
    __syncthreads();
    for (int off = 1; off < 512; off <<= 1) {
        int a = (t >= off) ? tmp[t - off] : 0;
        __syncthreads();
        tmp[t] += a;
        __syncthreads();
    }
    if (t < NB_SCAN) boffs[t] = tmp[t] - v;  // exclusive
}

__global__ void scan_final(const int* __restrict__ deg, const int* __restrict__ boffs,
                           int* __restrict__ rp) {
    __shared__ int tmp[256];
    int t = threadIdx.x;
    int i = blockIdx.x * 256 + t;
    int val = (i < N_NODES) ? deg[i] : 0;
    tmp[t] = val;
    __syncthreads();
    for (int off = 1; off < 256; off <<= 1) {
        int a = (t >= off) ? tmp[t - off] : 0;
        __syncthreads();
        tmp[t] += a;
        __syncthreads();
    }
    int excl = tmp[t] - val + boffs[blockIdx.x];
    if (i < N_NODES) {
        rp[i] = excl;
        if (i == N_NODES - 1) rp[N_NODES] = excl + val;
    }
}

// ---------------------------------------------------------------------------
// Gather + fused BN stats: z[v] = bias + T[v] + sum_u T[u]  (T bf16).
// ---------------------------------------------------------------------------
__device__ __forceinline__ float4 ld_bf4(const ushort* __restrict__ T, int u, int q) {
    ushort4 w = *(const ushort4*)(T + (size_t)u * HID + q * 4);
    float4 r;
    r.x = bf2f(w.x); r.y = bf2f(w.y); r.z = bf2f(w.z); r.w = bf2f(w.w);
    return r;
}

__global__ __launch_bounds__(192) void gather_stats(const ushort* __restrict__ T,
                                                    const int* __restrict__ rp,
                                                    const int* __restrict__ cols,
                                                    const float* __restrict__ bias,
                                                    float* __restrict__ z,
                                                    float* __restrict__ psums,
                                                    float* __restrict__ psq) {
    const int q = threadIdx.x % 24, rs = threadIdx.x / 24;
    const float4 bias4 = ((const float4*)bias)[q];
    float4 s = make_float4(0.f, 0.f, 0.f, 0.f);
    float4 sq = make_float4(0.f, 0.f, 0.f, 0.f);

    for (int v = blockIdx.x * 8 + rs; v < N_NODES; v += NB_GATH * 8) {
        float4 acc = bias4;
        acc4(acc, ld_bf4(T, v, q));
        int beg = rp[v], end = rp[v + 1];
        int j = beg;
        for (; j + 3 < end; j += 4) {
            int u0 = cols[j], u1 = cols[j + 1], u2 = cols[j + 2], u3 = cols[j + 3];
            acc4(acc, ld_bf4(T, u0, q));
            acc4(acc, ld_bf4(T, u1, q));
            acc4(acc, ld_bf4(T, u2, q));
            acc4(acc, ld_bf4(T, u3, q));
        }
        for (; j < end; ++j) acc4(acc, ld_bf4(T, cols[j], q));
        ((float4*)z)[(size_t)v * 24 + q] = acc;
        s.x += acc.x; s.y += acc.y; s.z += acc.z; s.w += acc.w;
        sq.x = fmaf(acc.x, acc.x, sq.x);
        sq.y = fmaf(acc.y, acc.y, sq.y);
        sq.z = fmaf(acc.z, acc.z, sq.z);
        sq.w = fmaf(acc.w, acc.w, sq.w);
    }

    __shared__ float4 ls[8][24], lq[8][24];
    ls[rs][q] = s;
    lq[rs][q] = sq;
    __syncthreads();
    if (threadIdx.x < 24) {
        float4 S = ls[0][threadIdx.x], Q = lq[0][threadIdx.x];
#pragma unroll
        for (int i = 1; i < 8; ++i) {
            acc4(S, ls[i][threadIdx.x]);
            acc4(Q, lq[i][threadIdx.x]);
        }
        ((float4*)(psums + (size_t)blockIdx.x * HID))[threadIdx.x] = S;
        ((float4*)(psq + (size_t)blockIdx.x * HID))[threadIdx.x] = Q;
    }
}

// ---------------------------------------------------------------------------
__global__ __launch_bounds__(384) void bn_finalize(const float* __restrict__ psums,
                                                   const float* __restrict__ psq,
                                                   const float* __restrict__ g,
                                                   const float* __restrict__ be,
                                                   float* __restrict__ scale,
                                                   float* __restrict__ shift) {
    int c = threadIdx.x % 96, h = threadIdx.x / 96;
    float S = 0.f, Q = 0.f;
    for (int b = h * (NB_GATH / 4); b < (h + 1) * (NB_GATH / 4); ++b) {
        S += psums[(size_t)b * HID + c];
        Q += psq[(size_t)b * HID + c];
    }
    __shared__ float lS[4][96], lQ[4][96];
    lS[h][c] = S;
    lQ[h][c] = Q;
    __syncthreads();
    if (threadIdx.x < 96) {
        S = lS[0][c] + lS[1][c] + lS[2][c] + lS[3][c];
        Q = lQ[0][c] + lQ[1][c] + lQ[2][c] + lQ[3][c];
        float mu = S * (1.0f / N_NODES);
        float var = Q * (1.0f / N_NODES) - mu * mu;
        float rstd = rsqrtf(var + 1e-5f);
        float sc = g[c] * rstd;
        scale[c] = sc;
        shift[c] = be[c] - mu * sc;
    }
}

// ---------------------------------------------------------------------------
// Readout: BN2+ReLU fused on input, LDS-tiled, 16 lanes/row log_softmax.
// ---------------------------------------------------------------------------
__global__ __launch_bounds__(256) void readout_kernel(const float* __restrict__ X,
                                                      const float* __restrict__ scale,
                                                      const float* __restrict__ shift,
                                                      const float* __restrict__ Wr,
                                                      const float* __restrict__ br,
                                                      float* __restrict__ out) {
    __shared__ float Ws[HID * NCLS];
    __shared__ float XL[16 * 97];
    __shared__ float scs[HID], shs[HID], bs[NCLS];
    for (int i = threadIdx.x; i < HID * NCLS / 4; i += 256)
        ((float4*)Ws)[i] = ((const float4*)Wr)[i];
    if (threadIdx.x < HID) {
        scs[threadIdx.x] = scale[threadIdx.x];
        shs[threadIdx.x] = shift[threadIdx.x];
    }
    if (threadIdx.x < NCLS) bs[threadIdx.x] = br[threadIdx.x];

    int rr = threadIdx.x >> 4, t = threadIdx.x & 15;
    for (int tile = blockIdx.x; tile < N_NODES / 16; tile += gridDim.x) {
        int rbase = tile * 16;
        __syncthreads();
        for (int i = threadIdx.x; i < 16 * HID; i += 256) {
            int row = i / HID, col = i - row * HID;
            float z = fmaf(X[(size_t)rbase * HID + i], scs[col], shs[col]);
            XL[row * 97 + col] = fmaxf(z, 0.f);
        }
        __syncthreads();
        float acc = bs[t];
        const float* xrow = &XL[rr * 97];
#pragma unroll 4
        for (int k = 0; k < HID; ++k) acc = fmaf(xrow[k], Ws[k * NCLS + t], acc);
        float m = acc;
#pragma unroll
        for (int off = 8; off; off >>= 1) m = fmaxf(m, __shfl_xor(m, off, 16));
        float e = expf(acc - m);
        float s = e;
#pragma unroll
        for (int off = 8; off; off >>= 1) s += __shfl_xor(s, off, 16);
        float lse = m + logf(s);
        out[(size_t)rbase * NCLS + threadIdx.x] = acc - lse;
    }
}

// ---------------------------------------------------------------------------
extern "C" void kernel_launch(void* const* d_in, const int* in_sizes, int n_in,
                              void* d_out, int out_size, void* d_ws, size_t ws_size,
                              hipStream_t stream) {
    const float* h     = (const float*)d_in[0];
    const int*   src   = (const int*)d_in[1];
    const int*   dst   = (const int*)d_in[2];
    const float* W_emb = (const float*)d_in[3];
    const float* b_emb = (const float*)d_in[4];
    const float* W1    = (const float*)d_in[5];
    const float* b1    = (const float*)d_in[6];
    const float* g1    = (const float*)d_in[7];
    const float* be1   = (const float*)d_in[8];
    const float* W2    = (const float*)d_in[9];
    const float* b2    = (const float*)d_in[10];
    const float* g2    = (const float*)d_in[11];
    const float* be2   = (const float*)d_in[12];
    const float* Wr    = (const float*)d_in[13];
    const float* br    = (const float*)d_in[14];

    const size_t nh = (size_t)N_NODES * HID;
    float*  z    = (float*)d_ws;              // 38.4 MB (z1, then z2)
    ushort* T    = (ushort*)(z + nh);         // 19.2 MB bf16 table
    int* deg     = (int*)(T + nh);            // N
    int* rp      = deg + N_NODES;             // N+1
    int* cols    = rp + N_NODES + 1;          // E
    int* bcur    = cols + N_EDGES;            // NBUK (pad to 1024)
    int* bsrc    = bcur + 1024;               // NBUK*BCAP (8.0 MB)
    int* bdst    = bsrc + (size_t)NBUK * BCAP;// NBUK*BCAP (8.0 MB)
    int* bsums   = bdst + (size_t)NBUK * BCAP;// 512
    int* boffs   = bsums + 512;               // 512
    float* psums = (float*)(boffs + 512);     // NB_GATH*96
    float* psq   = psums + (size_t)NB_GATH * HID;
    float* scale = psq + (size_t)NB_GATH * HID;   // 96
    float* shift = scale + HID;                    // 96
    float* Wf    = shift + HID;                    // 128*96
    float* bf    = Wf + IN_DIM * HID;              // 96

    const int blkT = (N_NODES + 127) / 128;   // 782
    const int blkE4 = (N_EDGES / 4 + 255) / 256;  // 1563

    // --- CSR build: bucket-partition -> local hist -> scan -> local place ---
    hipMemsetAsync(bcur, 0, NBUK * sizeof(int), stream);
    bucket_scatter<<<blkE4, 256, 0, stream>>>(src, dst, bcur, bsrc, bdst);
    bucket_hist<<<NBUK, 256, 0, stream>>>(bdst, bcur, deg);
    scan_blocksum<<<NB_SCAN, 256, 0, stream>>>(deg, bsums);
    scan_offsets<<<1, 512, 0, stream>>>(bsums, boffs);
    scan_final<<<NB_SCAN, 256, 0, stream>>>(deg, boffs, rp);
    bucket_place<<<NBUK, 256, 0, stream>>>(bsrc, bdst, bcur, rp, cols);
    wfuse<<<(IN_DIM * HID + 255) / 256, 256, 0, stream>>>(W_emb, W1, b_emb, Wf, bf);

    // --- layer 1: T1 = h @ Wf + bf (bf16);  z1 = gather(T1) + b1 (+stats) ---
    hipLaunchKernelGGL((gemm_bf16<IN_DIM, false>), dim3(blkT), dim3(192), 0, stream,
                       h, Wf, bf, nullptr, nullptr, T);
    gather_stats<<<NB_GATH, 192, 0, stream>>>(T, rp, cols, b1, z, psums, psq);
    bn_finalize<<<1, 384, 0, stream>>>(psums, psq, g1, be1, scale, shift);

    // --- layer 2: T2 = bn_relu(z1) @ W2 (bf16);  z2 = gather(T2) + b2 ---
    hipLaunchKernelGGL((gemm_bf16<HID, true>), dim3(blkT), dim3(192), 0, stream,
                       z, W2, nullptr, scale, shift, T);
    gather_stats<<<NB_GATH, 192, 0, stream>>>(T, rp, cols, b2, z, psums, psq);
    bn_finalize<<<1, 384, 0, stream>>>(psums, psq, g2, be2, scale, shift);

    // --- readout (BN2+ReLU fused) + log_softmax ---
    readout_kernel<<<2048, 256, 0, stream>>>(z, scale, shift, Wr, br, (float*)d_out);
}

// Round 9
// 382.546 us; speedup vs baseline: 1.9698x; 1.9698x over previous
//
#include <hip/hip_runtime.h>
#include <cmath>

#define N_NODES 100000
#define N_EDGES 1600000
#define IN_DIM 128
#define HID 96
#define NCLS 16
#define NB_SCAN 391   // ceil(N_NODES/256)
#define NB_GATH 2048  // gather grid (fixed, for stats partials)

// bucket-sort CSR build (contention-free)
#define BSHIFT 7
#define BNODES 128                 // nodes per bucket
#define NBUK 782                   // ceil(N_NODES/128)
#define TILE_E 16384               // edges per tile
#define NBLK_E 98                  // ceil(N_EDGES/TILE_E)
#define NBLK_Q 12                  // NBLK_E/8
#define NBLK_R 2                   // NBLK_E%8

typedef unsigned int uint;
typedef unsigned short ushort;

__device__ __forceinline__ ushort f2bf(float x) {  // RNE f32->bf16
    uint b = __float_as_uint(x);
    uint r = (b + 0x7FFFu + ((b >> 16) & 1u)) >> 16;
    return (ushort)r;
}
__device__ __forceinline__ float bf2f(ushort u) {
    return __uint_as_float(((uint)u) << 16);
}
__device__ __forceinline__ float4 bn_relu4(float4 x, float4 sc, float4 sh) {
    float4 r;
    r.x = fmaxf(fmaf(x.x, sc.x, sh.x), 0.f);
    r.y = fmaxf(fmaf(x.y, sc.y, sh.y), 0.f);
    r.z = fmaxf(fmaf(x.z, sc.z, sh.z), 0.f);
    r.w = fmaxf(fmaf(x.w, sc.w, sh.w), 0.f);
    return r;
}
__device__ __forceinline__ void acc4(float4& a, float4 x) {
    a.x += x.x; a.y += x.y; a.z += x.z; a.w += x.w;
}

// XCD-swizzled tile mapping: consecutive tiles land on the same XCD so
// adjacent (tile,bucket) output runs share L2 (boundary lines stay local).
// Bijective for NBLK_E = 8*NBLK_Q + NBLK_R.
__device__ __forceinline__ int tile_of(int blk) {
    int xcd = blk & 7, slot = blk >> 3;
    return (xcd < NBLK_R) ? xcd * (NBLK_Q + 1) + slot
                          : NBLK_R * (NBLK_Q + 1) + (xcd - NBLK_R) * NBLK_Q + slot;
}

// ---------------------------------------------------------------------------
// wfuse: Wf[128][96] = W_emb @ W1 ; bf[96] = b_emb @ W1
// ---------------------------------------------------------------------------
__global__ __launch_bounds__(256) void wfuse(const float* __restrict__ W_emb,
                                             const float* __restrict__ W1,
                                             const float* __restrict__ b_emb,
                                             float* __restrict__ Wf,
                                             float* __restrict__ bf) {
    __shared__ float W1s[HID * HID];
    for (int i = threadIdx.x; i < HID * HID / 4; i += 256)
        ((float4*)W1s)[i] = ((const float4*)W1)[i];
    __syncthreads();
    int idx = blockIdx.x * 256 + threadIdx.x;
    if (idx < IN_DIM * HID) {
        int i = idx / HID, j = idx - (idx / HID) * HID;
        float acc = 0.f;
        for (int k = 0; k < HID; ++k)
            acc = fmaf(W_emb[(size_t)i * HID + k], W1s[k * HID + j], acc);
        Wf[idx] = acc;
    }
    if (idx < HID) {
        float acc = 0.f;
        for (int k = 0; k < HID; ++k)
            acc = fmaf(b_emb[k], W1s[k * HID + idx], acc);
        bf[idx] = acc;
    }
}

// ---------------------------------------------------------------------------
// Tiled GEMM -> bf16 table (unchanged).
// ---------------------------------------------------------------------------
template <int K, bool BNIN>
__global__ __launch_bounds__(192) void gemm_bf16(const float* __restrict__ X,
                                                 const float* __restrict__ W,
                                                 const float* __restrict__ bias,
                                                 const float* __restrict__ scale,
                                                 const float* __restrict__ shift,
                                                 ushort* __restrict__ outB) {
    constexpr int GSTRIDE = K * 16 + 4;
    __shared__ float Ws[6 * GSTRIDE];
    __shared__ float bs[HID];
    __shared__ float scs[HID], shs[HID];
    for (int i = threadIdx.x; i < K * HID / 4; i += 192) {
        int flat = i * 4;
        int k = flat / HID, c = flat - k * HID;
        int g = c / 16, j = c - g * 16;
        *(float4*)&Ws[g * GSTRIDE + k * 16 + j] = ((const float4*)W)[i];
    }
    if (threadIdx.x < HID) {
        bs[threadIdx.x] = bias ? bias[threadIdx.x] : 0.f;
        if (BNIN) {
            scs[threadIdx.x] = scale[threadIdx.x];
            shs[threadIdx.x] = shift[threadIdx.x];
        }
    }
    __syncthreads();

    const int g = threadIdx.x % 6;
    const int rc = threadIdx.x / 6;
    const int rbase = blockIdx.x * 128 + rc * 4;
    const int r0 = min(rbase + 0, N_NODES - 1);
    const int r1 = min(rbase + 1, N_NODES - 1);
    const int r2 = min(rbase + 2, N_NODES - 1);
    const int r3 = min(rbase + 3, N_NODES - 1);
    const float* x0 = X + (size_t)r0 * K;
    const float* x1 = X + (size_t)r1 * K;
    const float* x2 = X + (size_t)r2 * K;
    const float* x3 = X + (size_t)r3 * K;
    const float* wg = Ws + g * GSTRIDE;

    float acc[4][16];
#pragma unroll
    for (int j = 0; j < 16; ++j) {
        float bj = bs[g * 16 + j];
        acc[0][j] = bj; acc[1][j] = bj; acc[2][j] = bj; acc[3][j] = bj;
    }

    for (int k = 0; k < K; k += 4) {
        float4 a0 = *(const float4*)(x0 + k);
        float4 a1 = *(const float4*)(x1 + k);
        float4 a2 = *(const float4*)(x2 + k);
        float4 a3 = *(const float4*)(x3 + k);
        if (BNIN) {
            float4 sc4 = *(const float4*)(scs + k);
            float4 sh4 = *(const float4*)(shs + k);
            a0 = bn_relu4(a0, sc4, sh4);
            a1 = bn_relu4(a1, sc4, sh4);
            a2 = bn_relu4(a2, sc4, sh4);
            a3 = bn_relu4(a3, sc4, sh4);
        }
#pragma unroll
        for (int kk = 0; kk < 4; ++kk) {
            const float* wrow = wg + (k + kk) * 16;
            float4 w0 = *(const float4*)(wrow + 0);
            float4 w1 = *(const float4*)(wrow + 4);
            float4 w2 = *(const float4*)(wrow + 8);
            float4 w3 = *(const float4*)(wrow + 12);
            float xs0 = kk == 0 ? a0.x : kk == 1 ? a0.y : kk == 2 ? a0.z : a0.w;
            float xs1 = kk == 0 ? a1.x : kk == 1 ? a1.y : kk == 2 ? a1.z : a1.w;
            float xs2 = kk == 0 ? a2.x : kk == 1 ? a2.y : kk == 2 ? a2.z : a2.w;
            float xs3 = kk == 0 ? a3.x : kk == 1 ? a3.y : kk == 2 ? a3.z : a3.w;
            const float wv[16] = {w0.x, w0.y, w0.z, w0.w, w1.x, w1.y, w1.z, w1.w,
                                  w2.x, w2.y, w2.z, w2.w, w3.x, w3.y, w3.z, w3.w};
#pragma unroll
            for (int j = 0; j < 16; ++j) {
                acc[0][j] = fmaf(xs0, wv[j], acc[0][j]);
                acc[1][j] = fmaf(xs1, wv[j], acc[1][j]);
                acc[2][j] = fmaf(xs2, wv[j], acc[2][j]);
                acc[3][j] = fmaf(xs3, wv[j], acc[3][j]);
            }
        }
    }
    const int rr[4] = {r0, r1, r2, r3};
    union PK { ushort u[8]; uint4 v; };
#pragma unroll
    for (int i = 0; i < 4; ++i) {
        ushort* orow = outB + (size_t)rr[i] * HID + g * 16;
        PK p0, p1;
#pragma unroll
        for (int j = 0; j < 8; ++j) {
            p0.u[j] = f2bf(acc[i][j]);
            p1.u[j] = f2bf(acc[i][j + 8]);
        }
        *(uint4*)(orow + 0) = p0.v;
        *(uint4*)(orow + 8) = p1.v;
    }
}

// ---------------------------------------------------------------------------
// CSR build, contention-free:
//   bin_hist:  per-tile LDS histogram over 782 buckets -> bcnt[buk][tile]
//   bin_scanA: per-bucket exclusive scan over tiles    -> boff, btot
//   bin_scanB: exclusive scan over buckets             -> bbase (bucket starts)
//   bin_scatter: deterministic disjoint ranges; LDS cursors; write packed
//                (src<<7)|(dst&127) into bucket-sorted ebuf.
// No contended global atomics anywhere (round-8 lesson: 2046 serialized
// RMWs per counter = 380us; exact-offset scatter has zero).
// ---------------------------------------------------------------------------
__global__ __launch_bounds__(256) void bin_hist(const int* __restrict__ dst,
                                                int* __restrict__ bcnt) {
    int tile = tile_of(blockIdx.x);
    int beg = tile * TILE_E, end = min(beg + TILE_E, N_EDGES);
    __shared__ int cnt[NBUK];
    for (int b = threadIdx.x; b < NBUK; b += 256) cnt[b] = 0;
    __syncthreads();
    for (int i = beg + threadIdx.x * 4; i < end; i += 256 * 4) {
        int4 d = *(const int4*)(dst + i);
        atomicAdd(&cnt[d.x >> BSHIFT], 1);
        atomicAdd(&cnt[d.y >> BSHIFT], 1);
        atomicAdd(&cnt[d.z >> BSHIFT], 1);
        atomicAdd(&cnt[d.w >> BSHIFT], 1);
    }
    __syncthreads();
    for (int b = threadIdx.x; b < NBUK; b += 256) bcnt[(size_t)b * NBLK_E + tile] = cnt[b];
}

__global__ __launch_bounds__(128) void bin_scanA(const int* __restrict__ bcnt,
                                                 int* __restrict__ boff,
                                                 int* __restrict__ btot) {
    int bin = blockIdx.x, t = threadIdx.x;
    __shared__ int tmp[128];
    int v = (t < NBLK_E) ? bcnt[(size_t)bin * NBLK_E + t] : 0;
    tmp[t] = v;
    __syncthreads();
    for (int off = 1; off < 128; off <<= 1) {
        int a = (t >= off) ? tmp[t - off] : 0;
        __syncthreads();
        tmp[t] += a;
        __syncthreads();
    }
    if (t < NBLK_E) boff[(size_t)bin * NBLK_E + t] = tmp[t] - v;
    if (t == NBLK_E - 1) btot[bin] = tmp[t];
}

__global__ __launch_bounds__(1024) void bin_scanB(const int* __restrict__ btot,
                                                  int* __restrict__ bbase) {
    int t = threadIdx.x;
    __shared__ int tmp[1024];
    int v = (t < NBUK) ? btot[t] : 0;
    tmp[t] = v;
    __syncthreads();
    for (int off = 1; off < 1024; off <<= 1) {
        int a = (t >= off) ? tmp[t - off] : 0;
        __syncthreads();
        tmp[t] += a;
        __syncthreads();
    }
    if (t < NBUK) bbase[t] = tmp[t] - v;
    if (t == 0) bbase[NBUK] = N_EDGES;
}

__global__ __launch_bounds__(256) void bin_scatter(const int* __restrict__ src,
                                                   const int* __restrict__ dst,
                                                   const int* __restrict__ bbase,
                                                   const int* __restrict__ boff,
                                                   int* __restrict__ ebuf) {
    int tile = tile_of(blockIdx.x);
    int beg = tile * TILE_E, end = min(beg + TILE_E, N_EDGES);
    __shared__ int curs[NBUK];
    for (int b = threadIdx.x; b < NBUK; b += 256)
        curs[b] = bbase[b] + boff[(size_t)b * NBLK_E + tile];
    __syncthreads();
    for (int i = beg + threadIdx.x * 4; i < end; i += 256 * 4) {
        int4 d = *(const int4*)(dst + i);
        int4 s = *(const int4*)(src + i);
#pragma unroll
        for (int e = 0; e < 4; ++e) {
            int dv = e == 0 ? d.x : e == 1 ? d.y : e == 2 ? d.z : d.w;
            int sv = e == 0 ? s.x : e == 1 ? s.y : e == 2 ? s.z : s.w;
            int p = atomicAdd(&curs[dv >> BSHIFT], 1);  // LDS atomic: cheap
            ebuf[p] = (sv << BSHIFT) | (dv & (BNODES - 1));
        }
    }
}

// one block per bucket: LDS degree count from the bucket's contiguous run
__global__ __launch_bounds__(256) void bucket_hist(const int* __restrict__ ebuf,
                                                   const int* __restrict__ bbase,
                                                   int* __restrict__ deg) {
    int b = blockIdx.x;
    int lo = b << BSHIFT;
    __shared__ int cnt[BNODES];
    if (threadIdx.x < BNODES) cnt[threadIdx.x] = 0;
    __syncthreads();
    int beg = bbase[b], end = bbase[b + 1];
    for (int i = beg + threadIdx.x; i < end; i += 256)
        atomicAdd(&cnt[ebuf[i] & (BNODES - 1)], 1);
    __syncthreads();
    if (threadIdx.x < BNODES && lo + threadIdx.x < N_NODES)
        deg[lo + threadIdx.x] = cnt[threadIdx.x];
}

// one block per bucket: place into cols within the bucket's 8KB window
__global__ __launch_bounds__(256) void bucket_place(const int* __restrict__ ebuf,
                                                    const int* __restrict__ bbase,
                                                    const int* __restrict__ rp,
                                                    int* __restrict__ cols) {
    int b = blockIdx.x;
    int lo = b << BSHIFT;
    __shared__ int cur[BNODES];
    if (threadIdx.x < BNODES)
        cur[threadIdx.x] = (lo + threadIdx.x < N_NODES) ? rp[lo + threadIdx.x] : 0;
    __syncthreads();
    int beg = bbase[b], end = bbase[b + 1];
    for (int i = beg + threadIdx.x; i < end; i += 256) {
        int v = ebuf[i];
        int p = atomicAdd(&cur[v & (BNODES - 1)], 1);
        cols[p] = v >> BSHIFT;
    }
}

// ---------------------------------------------------------------------------
// Scan (2-level) over deg -> rp
// ---------------------------------------------------------------------------
__global__ void scan_blocksum(const int* __restrict__ deg, int* __restrict__ bsums) {
    __shared__ int sm[256];
    int t = threadIdx.x;
    int i = blockIdx.x * 256 + t;
    sm[t] = (i < N_NODES) ? deg[i] : 0;
    __syncthreads();
    for (int s = 128; s > 0; s >>= 1) {
        if (t < s) sm[t] += sm[t + s];
        __syncthreads();
    }
    if (t == 0) bsums[blockIdx.x] = sm[0];
}

__global__ void scan_offsets(const int* __restrict__ bsums, int* __restrict__ boffs) {
    __shared__ int tmp[512];
    int t = threadIdx.x;
    int v = (t < NB_SCAN) ? bsums[t] : 0;
    tmp[t] = v;
    __syncthreads();
    for (int off = 1; off < 512; off <<= 1) {
        int a = (t >= off) ? tmp[t - off] : 0;
        __syncthreads();
        tmp[t] += a;
        __syncthreads();
    }
    if (t < NB_SCAN) boffs[t] = tmp[t] - v;  // exclusive
}

__global__ void scan_final(const int* __restrict__ deg, const int* __restrict__ boffs,
                           int* __restrict__ rp) {
    __shared__ int tmp[256];
    int t = threadIdx.x;
    int i = blockIdx.x * 256 + t;
    int val = (i < N_NODES) ? deg[i] : 0;
    tmp[t] = val;
    __syncthreads();
    for (int off = 1; off < 256; off <<= 1) {
        int a = (t >= off) ? tmp[t - off] : 0;
        __syncthreads();
        tmp[t] += a;
        __syncthreads();
    }
    int excl = tmp[t] - val + boffs[blockIdx.x];
    if (i < N_NODES) {
        rp[i] = excl;
        if (i == N_NODES - 1) rp[N_NODES] = excl + val;
    }
}

// ---------------------------------------------------------------------------
// Gather + fused BN stats: z[v] = bias + T[v] + sum_u T[u]  (T bf16).
// ---------------------------------------------------------------------------
__device__ __forceinline__ float4 ld_bf4(const ushort* __restrict__ T, int u, int q) {
    ushort4 w = *(const ushort4*)(T + (size_t)u * HID + q * 4);
    float4 r;
    r.x = bf2f(w.x); r.y = bf2f(w.y); r.z = bf2f(w.z); r.w = bf2f(w.w);
    return r;
}

__global__ __launch_bounds__(192) void gather_stats(const ushort* __restrict__ T,
                                                    const int* __restrict__ rp,
                                                    const int* __restrict__ cols,
                                                    const float* __restrict__ bias,
                                                    float* __restrict__ z,
                                                    float* __restrict__ psums,
                                                    float* __restrict__ psq) {
    const int q = threadIdx.x % 24, rs = threadIdx.x / 24;
    const float4 bias4 = ((const float4*)bias)[q];
    float4 s = make_float4(0.f, 0.f, 0.f, 0.f);
    float4 sq = make_float4(0.f, 0.f, 0.f, 0.f);

    for (int v = blockIdx.x * 8 + rs; v < N_NODES; v += NB_GATH * 8) {
        float4 acc = bias4;
        acc4(acc, ld_bf4(T, v, q));
        int beg = rp[v], end = rp[v + 1];
        int j = beg;
        for (; j + 3 < end; j += 4) {
            int u0 = cols[j], u1 = cols[j + 1], u2 = cols[j + 2], u3 = cols[j + 3];
            acc4(acc, ld_bf4(T, u0, q));
            acc4(acc, ld_bf4(T, u1, q));
            acc4(acc, ld_bf4(T, u2, q));
            acc4(acc, ld_bf4(T, u3, q));
        }
        for (; j < end; ++j) acc4(acc, ld_bf4(T, cols[j], q));
        ((float4*)z)[(size_t)v * 24 + q] = acc;
        s.x += acc.x; s.y += acc.y; s.z += acc.z; s.w += acc.w;
        sq.x = fmaf(acc.x, acc.x, sq.x);
        sq.y = fmaf(acc.y, acc.y, sq.y);
        sq.z = fmaf(acc.z, acc.z, sq.z);
        sq.w = fmaf(acc.w, acc.w, sq.w);
    }

    __shared__ float4 ls[8][24], lq[8][24];
    ls[rs][q] = s;
    lq[rs][q] = sq;
    __syncthreads();
    if (threadIdx.x < 24) {
        float4 S = ls[0][threadIdx.x], Q = lq[0][threadIdx.x];
#pragma unroll
        for (int i = 1; i < 8; ++i) {
            acc4(S, ls[i][threadIdx.x]);
            acc4(Q, lq[i][threadIdx.x]);
        }
        ((float4*)(psums + (size_t)blockIdx.x * HID))[threadIdx.x] = S;
        ((float4*)(psq + (size_t)blockIdx.x * HID))[threadIdx.x] = Q;
    }
}

// ---------------------------------------------------------------------------
__global__ __launch_bounds__(384) void bn_finalize(const float* __restrict__ psums,
                                                   const float* __restrict__ psq,
                                                   const float* __restrict__ g,
                                                   const float* __restrict__ be,
                                                   float* __restrict__ scale,
                                                   float* __restrict__ shift) {
    int c = threadIdx.x % 96, h = threadIdx.x / 96;
    float S = 0.f, Q = 0.f;
    for (int b = h * (NB_GATH / 4); b < (h + 1) * (NB_GATH / 4); ++b) {
        S += psums[(size_t)b * HID + c];
        Q += psq[(size_t)b * HID + c];
    }
    __shared__ float lS[4][96], lQ[4][96];
    lS[h][c] = S;
    lQ[h][c] = Q;
    __syncthreads();
    if (threadIdx.x < 96) {
        S = lS[0][c] + lS[1][c] + lS[2][c] + lS[3][c];
        Q = lQ[0][c] + lQ[1][c] + lQ[2][c] + lQ[3][c];
        float mu = S * (1.0f / N_NODES);
        float var = Q * (1.0f / N_NODES) - mu * mu;
        float rstd = rsqrtf(var + 1e-5f);
        float sc = g[c] * rstd;
        scale[c] = sc;
        shift[c] = be[c] - mu * sc;
    }
}

// ---------------------------------------------------------------------------
// Readout: BN2+ReLU fused on input, LDS-tiled, 16 lanes/row log_softmax.
// ---------------------------------------------------------------------------
__global__ __launch_bounds__(256) void readout_kernel(const float* __restrict__ X,
                                                      const float* __restrict__ scale,
                                                      const float* __restrict__ shift,
                                                      const float* __restrict__ Wr,
                                                      const float* __restrict__ br,
                                                      float* __restrict__ out) {
    __shared__ float Ws[HID * NCLS];
    __shared__ float XL[16 * 97];
    __shared__ float scs[HID], shs[HID], bs[NCLS];
    for (int i = threadIdx.x; i < HID * NCLS / 4; i += 256)
        ((float4*)Ws)[i] = ((const float4*)Wr)[i];
    if (threadIdx.x < HID) {
        scs[threadIdx.x] = scale[threadIdx.x];
        shs[threadIdx.x] = shift[threadIdx.x];
    }
    if (threadIdx.x < NCLS) bs[threadIdx.x] = br[threadIdx.x];

    int rr = threadIdx.x >> 4, t = threadIdx.x & 15;
    for (int tile = blockIdx.x; tile < N_NODES / 16; tile += gridDim.x) {
        int rbase = tile * 16;
        __syncthreads();
        for (int i = threadIdx.x; i < 16 * HID; i += 256) {
            int row = i / HID, col = i - row * HID;
            float z = fmaf(X[(size_t)rbase * HID + i], scs[col], shs[col]);
            XL[row * 97 + col] = fmaxf(z, 0.f);
        }
        __syncthreads();
        float acc = bs[t];
        const float* xrow = &XL[rr * 97];
#pragma unroll 4
        for (int k = 0; k < HID; ++k) acc = fmaf(xrow[k], Ws[k * NCLS + t], acc);
        float m = acc;
#pragma unroll
        for (int off = 8; off; off >>= 1) m = fmaxf(m, __shfl_xor(m, off, 16));
        float e = expf(acc - m);
        float s = e;
#pragma unroll
        for (int off = 8; off; off >>= 1) s += __shfl_xor(s, off, 16);
        float lse = m + logf(s);
        out[(size_t)rbase * NCLS + threadIdx.x] = acc - lse;
    }
}

// ---------------------------------------------------------------------------
extern "C" void kernel_launch(void* const* d_in, const int* in_sizes, int n_in,
                              void* d_out, int out_size, void* d_ws, size_t ws_size,
                              hipStream_t stream) {
    const float* h     = (const float*)d_in[0];
    const int*   src   = (const int*)d_in[1];
    const int*   dst   = (const int*)d_in[2];
    const float* W_emb = (const float*)d_in[3];
    const float* b_emb = (const float*)d_in[4];
    const float* W1    = (const float*)d_in[5];
    const float* b1    = (const float*)d_in[6];
    const float* g1    = (const float*)d_in[7];
    const float* be1   = (const float*)d_in[8];
    const float* W2    = (const float*)d_in[9];
    const float* b2    = (const float*)d_in[10];
    const float* g2    = (const float*)d_in[11];
    const float* be2   = (const float*)d_in[12];
    const float* Wr    = (const float*)d_in[13];
    const float* br    = (const float*)d_in[14];

    const size_t nh = (size_t)N_NODES * HID;
    float*  z    = (float*)d_ws;              // 38.4 MB (z1, then z2)
    ushort* T    = (ushort*)(z + nh);         // 19.2 MB bf16 table
    int* deg     = (int*)(T + nh);            // N
    int* rp      = deg + N_NODES;             // N+1
    int* cols    = rp + N_NODES + 1;          // E (6.4 MB)
    int* ebuf    = cols + N_EDGES;            // E (6.4 MB, bucket-sorted packed)
    int* bcnt    = ebuf + N_EDGES;            // NBUK*NBLK_E
    int* boff    = bcnt + NBUK * NBLK_E;      // NBUK*NBLK_E
    int* btot    = boff + NBUK * NBLK_E;      // NBUK
    int* bbase   = btot + NBUK;               // NBUK+1
    int* bsums   = bbase + NBUK + 1;          // 512
    int* boffs   = bsums + 512;               // 512
    float* psums = (float*)(boffs + 512);     // NB_GATH*96
    float* psq   = psums + (size_t)NB_GATH * HID;
    float* scale = psq + (size_t)NB_GATH * HID;   // 96
    float* shift = scale + HID;                    // 96
    float* Wf    = shift + HID;                    // 128*96
    float* bf    = Wf + IN_DIM * HID;              // 96

    const int blkT = (N_NODES + 127) / 128;   // 782

    // --- CSR build: tile-hist -> scans -> deterministic scatter -> place ---
    bin_hist<<<NBLK_E, 256, 0, stream>>>(dst, bcnt);
    bin_scanA<<<NBUK, 128, 0, stream>>>(bcnt, boff, btot);
    bin_scanB<<<1, 1024, 0, stream>>>(btot, bbase);
    bin_scatter<<<NBLK_E, 256, 0, stream>>>(src, dst, bbase, boff, ebuf);
    bucket_hist<<<NBUK, 256, 0, stream>>>(ebuf, bbase, deg);
    scan_blocksum<<<NB_SCAN, 256, 0, stream>>>(deg, bsums);
    scan_offsets<<<1, 512, 0, stream>>>(bsums, boffs);
    scan_final<<<NB_SCAN, 256, 0, stream>>>(deg, boffs, rp);
    bucket_place<<<NBUK, 256, 0, stream>>>(ebuf, bbase, rp, cols);
    wfuse<<<(IN_DIM * HID + 255) / 256, 256, 0, stream>>>(W_emb, W1, b_emb, Wf, bf);

    // --- layer 1: T1 = h @ Wf + bf (bf16);  z1 = gather(T1) + b1 (+stats) ---
    hipLaunchKernelGGL((gemm_bf16<IN_DIM, false>), dim3(blkT), dim3(192), 0, stream,
                       h, Wf, bf, nullptr, nullptr, T);
    gather_stats<<<NB_GATH, 192, 0, stream>>>(T, rp, cols, b1, z, psums, psq);
    bn_finalize<<<1, 384, 0, stream>>>(psums, psq, g1, be1, scale, shift);

    // --- layer 2: T2 = bn_relu(z1) @ W2 (bf16);  z2 = gather(T2) + b2 ---
    hipLaunchKernelGGL((gemm_bf16<HID, true>), dim3(blkT), dim3(192), 0, stream,
                       z, W2, nullptr, scale, shift, T);
    gather_stats<<<NB_GATH, 192, 0, stream>>>(T, rp, cols, b2, z, psums, psq);
    bn_finalize<<<1, 384, 0, stream>>>(psums, psq, g2, be2, scale, shift);

    // --- readout (BN2+ReLU fused) + log_softmax ---
    readout_kernel<<<2048, 256, 0, stream>>>(z, scale, shift, Wr, br, (float*)d_out);
}